// Round 1
// baseline (121.028 us; speedup 1.0000x reference)
//
#include <hip/hip_runtime.h>

// Problem constants (from reference)
constexpr int Ni = 4, Ci = 256, Hi = 256, Wi = 256;
constexpr int Bn = 512, PHn = 7, PWn = 7, SRn = 2;
constexpr float SCALEf = 0.25f;
constexpr int CCHUNK = 64;                 // channels per block
constexpr int NBINS = PHn * PWn;           // 49
constexpr int NSY = PHn * SRn;             // 14 y samples
constexpr int NSX = PWn * SRn;             // 14 x samples

__global__ __launch_bounds__(256) void roialign_kernel(
    const float* __restrict__ input,
    const float* __restrict__ rois,
    float* __restrict__ out)
{
    const int blk = blockIdx.x;
    const int b = blk / (Ci / CCHUNK);
    const int chunk = blk % (Ci / CCHUNK);

    __shared__ int   s_ylo[NSY], s_yhi[NSY], s_yv[NSY];
    __shared__ float s_lyf[NSY];
    __shared__ int   s_xlo[NSX], s_xhi[NSX], s_xv[NSX];
    __shared__ float s_lxf[NSX];
    __shared__ int   s_bidx;

    const int t = threadIdx.x;

    // Precompute per-ROI sample indices/weights (exactly mirrors _interp_1d)
    if (t < NSY + NSX) {
        const float r0  = rois[b * 5 + 0];
        const float rx1 = rois[b * 5 + 1];
        const float ry1 = rois[b * 5 + 2];
        const float rx2 = rois[b * 5 + 3];
        const float ry2 = rois[b * 5 + 4];
        const float x1 = rx1 * SCALEf - 0.5f;
        const float y1 = ry1 * SCALEf - 0.5f;
        const float x2 = rx2 * SCALEf - 0.5f;
        const float y2 = ry2 * SCALEf - 0.5f;
        const float bin_w = (x2 - x1) / (float)PWn;
        const float bin_h = (y2 - y1) / (float)PHn;
        if (t == 0) s_bidx = (int)r0;

        const bool isY = (t < NSY);
        const int  s   = isY ? t : (t - NSY);
        const int  p   = s / SRn;
        const int  i   = s % SRn;
        const float off   = ((float)i + 0.5f) / (float)SRn;
        const float start = isY ? y1 : x1;
        const float binsz = isY ? bin_h : bin_w;
        const float c     = start + ((float)p + off) * binsz;
        const int   size  = isY ? Hi : Wi;

        const bool  valid = (c >= -1.0f) && (c <= (float)size);
        const float cc    = fmaxf(c, 0.0f);
        const float lo_f  = floorf(cc);
        int lo = min((int)lo_f, size - 1);
        int hi = min(lo + 1, size - 1);
        const float c_adj = (lo_f >= (float)(size - 1)) ? (float)(size - 1) : cc;
        const float frac  = c_adj - (float)lo;

        if (isY) { s_ylo[s] = lo; s_yhi[s] = hi; s_lyf[s] = frac; s_yv[s] = valid ? 1 : 0; }
        else     { s_xlo[s] = lo; s_xhi[s] = hi; s_lxf[s] = frac; s_xv[s] = valid ? 1 : 0; }
    }
    __syncthreads();

    const int bidx = s_bidx;
    const int nelem = CCHUNK * NBINS;  // 3136

    for (int o = t; o < nelem; o += 256) {
        const int cl  = o / NBINS;
        const int bin = o % NBINS;
        const int ph  = bin / PWn;
        const int pw  = bin % PWn;
        const int c   = chunk * CCHUNK + cl;

        const float* plane = input + ((size_t)bidx * Ci + c) * (size_t)(Hi * Wi);

        float acc = 0.0f;
        #pragma unroll
        for (int iy = 0; iy < SRn; ++iy) {
            const int   sy  = ph * SRn + iy;
            const int   ylo = s_ylo[sy];
            const int   yhi = s_yhi[sy];
            const float ly  = s_lyf[sy];
            const float hy  = 1.0f - ly;
            const int   vy  = s_yv[sy];
            #pragma unroll
            for (int ix = 0; ix < SRn; ++ix) {
                const int   sx  = pw * SRn + ix;
                const int   xlo = s_xlo[sx];
                const int   xhi = s_xhi[sx];
                const float lx  = s_lxf[sx];
                const float hx  = 1.0f - lx;
                if (vy && s_xv[sx]) {
                    const float v11 = plane[ylo * Wi + xlo];
                    const float v12 = plane[ylo * Wi + xhi];
                    const float v21 = plane[yhi * Wi + xlo];
                    const float v22 = plane[yhi * Wi + xhi];
                    acc += hy * (hx * v11 + lx * v12) + ly * (hx * v21 + lx * v22);
                }
            }
        }
        out[(((size_t)b * Ci + c) * PHn + ph) * PWn + pw] = acc * (1.0f / (SRn * SRn));
    }
}

extern "C" void kernel_launch(void* const* d_in, const int* in_sizes, int n_in,
                              void* d_out, int out_size, void* d_ws, size_t ws_size,
                              hipStream_t stream) {
    const float* input = (const float*)d_in[0];
    const float* rois  = (const float*)d_in[1];
    float* out = (float*)d_out;

    const int grid = Bn * (Ci / CCHUNK);  // 2048 blocks
    roialign_kernel<<<grid, 256, 0, stream>>>(input, rois, out);
}